// Round 20
// baseline (122.017 us; speedup 1.0000x reference)
//
#include <hip/hip_runtime.h>

typedef unsigned short u16;
typedef __attribute__((ext_vector_type(8))) short bf16x8;
typedef __attribute__((ext_vector_type(4))) short bf16x4;
typedef __attribute__((ext_vector_type(4))) float f32x4;

#define NB 2
#define SEQ 2048
#define HID 1024
#define NHEAD 16
#define HD 64
#define MROWS (NB * SEQ) /* 4096 */

__device__ __forceinline__ float bf2f(u16 u) {
  union { unsigned u; float f; } x; x.u = ((unsigned)u) << 16; return x.f;
}
__device__ __forceinline__ u16 f2bf(float f) {
  union { float f; unsigned u; } x; x.f = f;
  unsigned r = x.u + 0x7fffu + ((x.u >> 16) & 1u);
  return (u16)(r >> 16);
}
__device__ __forceinline__ u16 f2bf_trunc(float f) {
  union { float f; unsigned u; } x; x.f = f;
  return (u16)(x.u >> 16);
}

#define GLOAD_LDS16(g, l)                                                   \
  __builtin_amdgcn_global_load_lds(                                         \
      (const __attribute__((address_space(1))) void*)(g),                   \
      (__attribute__((address_space(3))) void*)(l), 16, 0, 0)

// all-tensor f32 -> bf16: q,k,v (4M elems each) + Wq,Wk,Wv -> Wcat + Wp -> Wpb
__global__ __launch_bounds__(256)
void conv_all(const float* __restrict__ q, const float* __restrict__ k,
              const float* __restrict__ v, const float* __restrict__ wq,
              const float* __restrict__ wk, const float* __restrict__ wv,
              const float* __restrict__ wp, u16* __restrict__ qb,
              u16* __restrict__ kb, u16* __restrict__ vb,
              u16* __restrict__ wcat, u16* __restrict__ wpb)
{
  const int i = blockIdx.x * 256 + threadIdx.x;  // vec8 index, < 2097152
  const float* s; u16* d;
  if (i < 1572864) {
    const int seg = i / 524288;          // 0=q 1=k 2=v
    const int off = i - seg * 524288;
    s = (seg == 0 ? q : seg == 1 ? k : v) + (size_t)off * 8;
    d = (seg == 0 ? qb : seg == 1 ? kb : vb) + (size_t)off * 8;
  } else {
    const int j = i - 1572864;
    const int seg = j / 131072;          // 0=Wq 1=Wk 2=Wv 3=Wp
    const int off = j - seg * 131072;
    s = (seg == 0 ? wq : seg == 1 ? wk : seg == 2 ? wv : wp) + (size_t)off * 8;
    d = (seg < 3 ? wcat + (size_t)seg * 1048576 : wpb) + (size_t)off * 8;
  }
  f32x4 a = *(const f32x4*)s;
  f32x4 b = *(const f32x4*)(s + 4);
  bf16x8 o;
#pragma unroll
  for (int j = 0; j < 4; ++j) { o[j] = (short)f2bf(a[j]); o[4 + j] = (short)f2bf(b[j]); }
  *(bf16x8*)d = o;
}

// Fused QKV projection GEMM, 128x128x32. 3-buffer, 2-ahead prefetch,
// counted vmcnt(4) (R18/R19 — ~neutral-to-better vs 2-buffer, kept).
// LDS 48 KB, 3 blocks/CU uniform (grid 768). XOR chunk swizzle
// (chunk ^= (row>>1)&3, pre-swizzled source). XCD-pinned groups. bf16 A.
__global__ __launch_bounds__(256)
void gemm_qkv(const u16* __restrict__ A0, const u16* __restrict__ A1,
              const u16* __restrict__ A2, const u16* __restrict__ Wcat,
              const float* __restrict__ b0, const float* __restrict__ b1,
              const float* __restrict__ b2,
              u16* __restrict__ Qh, u16* __restrict__ Kh, u16* __restrict__ Vt,
              float qscale)
{
  __shared__ u16 As[3 * 128 * 32];   // 24 KB (3 bufs x 8 KB)
  __shared__ u16 Bs[3 * 128 * 32];   // 24 KB
  const int p = blockIdx.x;
  const int c = p & 7;                 // presumed XCD (round-robin dispatch)
  const int i_ = p >> 3;               // [0,96)
  const int G = c * 12 + (i_ % 12);    // group: 8 members share A rows + XCD
  const int j = i_ / 12;               // member = n-subtile [0,8)
  const int g = G >> 5;                // tensor select 0..2 (q/k/v)
  const int m0 = (G & 31) * 128;       // m-tile
  const int n0 = (g * 8 + j) * 128;    // Wcat row base
  const u16* A = (g == 0) ? A0 : (g == 1) ? A1 : A2;
  const float* bias = (g == 0) ? b0 : (g == 1) ? b1 : b2;
  const int t = threadIdx.x, lane = t & 63, w = t >> 6;
  const int grp = lane >> 4, lr = lane & 15;
  const int wr = (w >> 1) * 64, wc = (w & 1) * 64;
  const int sw2 = (lr >> 1) & 3;       // read-side XOR

  f32x4 acc[4][4];
#pragma unroll
  for (int i = 0; i < 4; ++i)
#pragma unroll
    for (int j2 = 0; j2 < 4; ++j2) acc[i][j2] = (f32x4){0.f, 0.f, 0.f, 0.f};

  const int srow4 = lane >> 2;
  const int csrc = ((lane & 3) ^ ((lane >> 3) & 3)) * 8;
  const u16* ag = A + (size_t)(m0 + w * 32 + srow4) * HID + csrc;
  const u16* wg = Wcat + (size_t)(n0 + w * 32 + srow4) * HID + csrc;

#define STAGE(BI, K0)                                                \
  {                                                                  \
    const u16* ab = ag + (K0);                                       \
    const u16* wb = wg + (K0);                                       \
    u16* al = As + (BI) * 4096 + (w * 32) * 32;                      \
    u16* bl = Bs + (BI) * 4096 + (w * 32) * 32;                      \
    GLOAD_LDS16(ab, al);                                             \
    GLOAD_LDS16(ab + (size_t)16 * HID, al + 16 * 32);                \
    GLOAD_LDS16(wb, bl);                                             \
    GLOAD_LDS16(wb + (size_t)16 * HID, bl + 16 * 32);                \
  }

  STAGE(0, 0);
  STAGE(1, 32);

  for (int it = 0; it < 32; ++it) {
    const int cur = it % 3;
    if (it < 31) asm volatile("s_waitcnt vmcnt(4)" ::: "memory");
    else         asm volatile("s_waitcnt vmcnt(0)" ::: "memory");
    __builtin_amdgcn_s_barrier();
    __builtin_amdgcn_sched_barrier(0);
    asm volatile("" ::: "memory");
    if (it < 30) STAGE((it + 2) % 3, (it + 2) * 32);
    const u16* Ab = As + cur * 4096;
    const u16* Bb = Bs + cur * 4096;
    bf16x8 af[4], bf[4];
#pragma unroll
    for (int mi = 0; mi < 4; ++mi)
      af[mi] = *(const bf16x8*)&Ab[(wr + mi * 16 + lr) * 32 +
                                   (((grp ^ sw2)) * 8)];
#pragma unroll
    for (int ni = 0; ni < 4; ++ni)
      bf[ni] = *(const bf16x8*)&Bb[(wc + ni * 16 + lr) * 32 +
                                   (((grp ^ sw2)) * 8)];
    __builtin_amdgcn_s_setprio(1);
#pragma unroll
    for (int mi = 0; mi < 4; ++mi)
#pragma unroll
      for (int ni = 0; ni < 4; ++ni)
        acc[mi][ni] = __builtin_amdgcn_mfma_f32_16x16x32_bf16(
            af[mi], bf[ni], acc[mi][ni], 0, 0, 0);
    __builtin_amdgcn_s_setprio(0);
  }
#undef STAGE

  const float scale = (g == 0) ? qscale : 1.f;
#pragma unroll
  for (int mi = 0; mi < 4; ++mi) {
#pragma unroll
    for (int ni = 0; ni < 4; ++ni) {
      const int nl = (n0 & (HID - 1)) + wc + ni * 16 + lr;  // within-tensor col
      const float bval = bias[nl];
      const int mb = m0 + wr + mi * 16 + grp * 4;
      const int h = nl >> 6, d = nl & (HD - 1);
      if (g == 2) {  // V transposed: vector over r (m-contiguous)
        const int b = mb >> 11, nn = mb & (SEQ - 1);
        bf16x4 pk;
#pragma unroll
        for (int r = 0; r < 4; ++r)
          pk[r] = (short)f2bf(acc[mi][ni][r] + bval);
        *(bf16x4*)&Vt[((size_t)(b * NHEAD + h) * HD + d) * SEQ + nn] = pk;
      } else {
        u16* O = (g == 0) ? Qh : Kh;
#pragma unroll
        for (int r = 0; r < 4; ++r) {
          const int m = mb + r;
          const int b = m >> 11, nn = m & (SEQ - 1);
          O[((size_t)(b * NHEAD + h) * SEQ + nn) * HD + d] =
              f2bf((acc[mi][ni][r] + bval) * scale);
        }
      }
    }
  }
}

// Output projection GEMM, 128x64x64 (R17, control — unchanged).
__global__ __launch_bounds__(256)
void gemm_proj(const u16* __restrict__ A, const u16* __restrict__ W,
               const float* __restrict__ bias, float* __restrict__ Op)
{
  __shared__ u16 As[2 * 128 * 64];   // 32 KB
  __shared__ u16 Bs[2 * 64 * 64];    // 16 KB
  const int p = blockIdx.x;
  const int cx = p & 7;
  const int i_ = p >> 3;               // [0,64)
  const int G = cx * 4 + (i_ & 3);     // m-tile [0,32), pinned to XCD cx
  const int j = i_ >> 2;               // n-member [0,16)
  const int m0 = G * 128, n0 = j * 64;
  const int t = threadIdx.x, lane = t & 63, w = t >> 6;
  const int grp = lane >> 4, lr = lane & 15;
  const int wr = (w >> 1) * 64, wc = (w & 1) * 32;
  const int sw8 = lr & 7;

  f32x4 acc[4][2];
#pragma unroll
  for (int i = 0; i < 4; ++i)
#pragma unroll
    for (int j2 = 0; j2 < 2; ++j2) acc[i][j2] = (f32x4){0.f, 0.f, 0.f, 0.f};

  const int srow8 = lane >> 3;
  const int achunk = ((lane & 7) ^ srow8) * 8;
  const u16* ag = A + (size_t)(m0 + w * 32 + srow8) * HID + achunk;
  const u16* wg = W + (size_t)(n0 + w * 16 + srow8) * HID + achunk;

#define STAGE(BI, K0)                                                \
  {                                                                  \
    const u16* ab = ag + (K0);                                       \
    const u16* wb = wg + (K0);                                       \
    u16* al = As + (BI) * 8192 + (w * 32) * 64;                      \
    u16* bl = Bs + (BI) * 4096 + (w * 16) * 64;                      \
    GLOAD_LDS16(ab, al);                                             \
    GLOAD_LDS16(ab + (size_t)8 * HID, al + 8 * 64);                  \
    GLOAD_LDS16(ab + (size_t)16 * HID, al + 16 * 64);                \
    GLOAD_LDS16(ab + (size_t)24 * HID, al + 24 * 64);                \
    GLOAD_LDS16(wb, bl);                                             \
    GLOAD_LDS16(wb + (size_t)8 * HID, bl + 8 * 64);                  \
  }

  STAGE(0, 0);

  for (int it = 0; it < 16; ++it) {
    const int cur = it & 1;
    asm volatile("s_waitcnt vmcnt(0)" ::: "memory");
    __builtin_amdgcn_s_barrier();
    __builtin_amdgcn_sched_barrier(0);
    asm volatile("" ::: "memory");
    if (it < 15) STAGE(cur ^ 1, (it + 1) * 64);
    const u16* Ab = As + cur * 8192;
    const u16* Bb = Bs + cur * 4096;
#pragma unroll
    for (int kh = 0; kh < 2; ++kh) {
      bf16x8 af[4], bf[2];
#pragma unroll
      for (int mi = 0; mi < 4; ++mi)
        af[mi] = *(const bf16x8*)&Ab[(wr + mi * 16 + lr) * 64 +
                                     (((kh * 4 + grp) ^ sw8) * 8)];
#pragma unroll
      for (int ni = 0; ni < 2; ++ni)
        bf[ni] = *(const bf16x8*)&Bb[(wc + ni * 16 + lr) * 64 +
                                     (((kh * 4 + grp) ^ sw8) * 8)];
      __builtin_amdgcn_s_setprio(1);
#pragma unroll
      for (int mi = 0; mi < 4; ++mi)
#pragma unroll
        for (int ni = 0; ni < 2; ++ni)
          acc[mi][ni] = __builtin_amdgcn_mfma_f32_16x16x32_bf16(
              af[mi], bf[ni], acc[mi][ni], 0, 0, 0);
      __builtin_amdgcn_s_setprio(0);
    }
  }
#undef STAGE

#pragma unroll
  for (int mi = 0; mi < 4; ++mi) {
#pragma unroll
    for (int ni = 0; ni < 2; ++ni) {
      const int n = n0 + wc + ni * 16 + lr;
      const float bval = bias[n];
      const int mb = m0 + wr + mi * 16 + grp * 4;
#pragma unroll
      for (int rr = 0; rr < 4; ++rr)
        Op[(size_t)(mb + rr) * HID + n] = acc[mi][ni][rr] + bval;
    }
  }
}

// Causal flash attention, PAIRED q-tiles + 3-WAY INTERLEAVED KV SPLIT.
// Additive no-max partials make N-way splits exact; part = px%3 owns kv
// tiles it = part, part+3, ... Grid 768 = 3 blocks/CU (was 2) -> a third
// block per CU absorbs the vmcnt(0)+barrier stalls. Each kv tile staged
// exactly once across siblings -> FETCH unchanged. 2-buffer LDS,
// QBLK=128 (8 waves x 16 q/stream), KVBLK=64.
__global__ __launch_bounds__(512)
void attn_fwd(const u16* __restrict__ Q, const u16* __restrict__ K,
              const u16* __restrict__ Vt, u16* __restrict__ parO,
              float* __restrict__ parL)
{
  __shared__ u16 KB[2][4096];
  __shared__ u16 VB[2][4096];
  const int bh = blockIdx.y;
  const int t = threadIdx.x;
  const int w = t >> 6, lane = t & 63;
  const int grp = lane >> 4, lr = lane & 15;
  const int px = blockIdx.x;           // [0,24)
  const int part = px % 3;             // kv residue class
  const int qtA = px / 3;              // 0..7
  const int qtB = 15 - qtA;            // 8..15
  const int q0A = qtA * 128 + w * 16;
  const int q0B = qtB * 128 + w * 16;
  const int ntB = 2 * qtB + 2;
  const size_t base = (size_t)bh * SEQ * HD;
  const float NEGINF = -__builtin_inff();

  const int srow = lane >> 3;
  const int scol = (lane & 7) ^ srow;
  const u16* kg = K + base + (size_t)(w * 8 + srow) * HD + scol * 8;
  const u16* vg = Vt + base + (size_t)(w * 8 + srow) * SEQ + scol * 8;

  const bf16x8 aqA0 = *(const bf16x8*)&Q[base + (size_t)(q0A + lr) * HD + grp * 8];
  const bf16x8 aqA1 = *(const bf16x8*)&Q[base + (size_t)(q0A + lr) * HD + grp * 8 + 32];
  const bf16x8 aqB0 = *(const bf16x8*)&Q[base + (size_t)(q0B + lr) * HD + grp * 8];
  const bf16x8 aqB1 = *(const bf16x8*)&Q[base + (size_t)(q0B + lr) * HD + grp * 8 + 32];

  float lA = 0.f, lB = 0.f;
  f32x4 oA[4], oB[4];
#pragma unroll
  for (int c = 0; c < 4; ++c) {
    oA[c] = (f32x4){0.f, 0.f, 0.f, 0.f};
    oB[c] = (f32x4){0.f, 0.f, 0.f, 0.f};
  }

  const int idqA = q0A >> 6;
  const int idqB = q0B >> 6;
  const int sw = lr & 7;

#define STAGE(bi, j0)                                              \
  {                                                                \
    GLOAD_LDS16(kg + (size_t)(j0) * HD, &KB[bi][w * 512]);         \
    GLOAD_LDS16(vg + (j0), &VB[bi][w * 512]);                      \
  }

#define COMPUTE(Q0, AQ0, AQ1, OACC, LI, IDQ)                                  \
  do {                                                                        \
    f32x4 sv[4];                                                              \
    __builtin_amdgcn_s_setprio(1);                                            \
    _Pragma("unroll")                                                         \
    for (int st = 0; st < 4; ++st) {                                          \
      const int ro = (st * 16 + lr) * 64;                                     \
      bf16x8 k0 = *(const bf16x8*)&KB[bi][ro + ((grp ^ sw) * 8)];             \
      bf16x8 k1 = *(const bf16x8*)&KB[bi][ro + (((grp + 4) ^ sw) * 8)];       \
      f32x4 s = (f32x4){0.f, 0.f, 0.f, 0.f};                                  \
      s = __builtin_amdgcn_mfma_f32_16x16x32_bf16(k0, (AQ0), s, 0, 0, 0);     \
      s = __builtin_amdgcn_mfma_f32_16x16x32_bf16(k1, (AQ1), s, 0, 0, 0);     \
      sv[st] = s;                                                             \
    }                                                                         \
    __builtin_amdgcn_s_setprio(0);                                            \
    bf16x4 bv[4][4];                                                          \
    _Pragma("unroll")                                                         \
    for (int st = 0; st < 4; ++st)                                            \
      _Pragma("unroll")                                                       \
      for (int c = 0; c < 4; ++c)                                             \
        bv[st][c] = *(const bf16x4*)&VB[bi][(c * 16 + lr) * 64 +              \
                        (((st * 2 + (grp >> 1)) ^ sw) * 8) + (grp & 1) * 4];  \
    if (it == (IDQ)) {                                                        \
      const int j0 = it << 6, qg = (Q0) + lr;                                 \
      _Pragma("unroll")                                                       \
      for (int st = 0; st < 4; ++st)                                          \
        _Pragma("unroll")                                                     \
        for (int r = 0; r < 4; ++r)                                           \
          if (j0 + st * 16 + grp * 4 + r > qg) sv[st][r] = NEGINF;            \
    }                                                                         \
    float rs = 0.f;                                                           \
    _Pragma("unroll")                                                         \
    for (int st = 0; st < 4; ++st)                                            \
      _Pragma("unroll")                                                       \
      for (int r = 0; r < 4; ++r) {                                           \
        sv[st][r] = exp2f(sv[st][r]);                                         \
        rs += sv[st][r];                                                      \
      }                                                                       \
    (LI) += rs;                                                               \
    bf16x4 pa[4];                                                             \
    _Pragma("unroll")                                                         \
    for (int st = 0; st < 4; ++st)                                            \
      _Pragma("unroll")                                                       \
      for (int r = 0; r < 4; ++r) pa[st][r] = (short)f2bf_trunc(sv[st][r]);   \
    __builtin_amdgcn_s_setprio(1);                                            \
    _Pragma("unroll")                                                         \
    for (int st = 0; st < 4; ++st)                                            \
      _Pragma("unroll")                                                       \
      for (int c = 0; c < 4; ++c)                                             \
        (OACC)[c] = __builtin_amdgcn_mfma_f32_16x16x16bf16_1k(                \
            pa[st], bv[st][c], (OACC)[c], 0, 0, 0);                           \
    __builtin_amdgcn_s_setprio(0);                                            \
  } while (0)

  STAGE(0, part << 6);

  for (int it = part; it < ntB; it += 3) {
    const int bi = ((it - part) / 3) & 1;
    asm volatile("s_waitcnt vmcnt(0)" ::: "memory");
    __builtin_amdgcn_s_barrier();
    __builtin_amdgcn_sched_barrier(0);
    asm volatile("" ::: "memory");
    if (it + 3 < ntB) STAGE(bi ^ 1, (it + 3) << 6);

    if (it <= idqB) COMPUTE(q0B, aqB0, aqB1, oB, lB, idqB);
    if (it <= idqA) COMPUTE(q0A, aqA0, aqA1, oA, lA, idqA);
  }
#undef STAGE
#undef COMPUTE

  lB += __shfl_xor(lB, 16);  lB += __shfl_xor(lB, 32);
  lA += __shfl_xor(lA, 16);  lA += __shfl_xor(lA, 32);

  const size_t pbase = (size_t)(part * 32 + bh) * SEQ;
  if (grp == 0) {
    parL[pbase + q0B + lr] = lB;
    parL[pbase + q0A + lr] = lA;
  }
#pragma unroll
  for (int r = 0; r < 4; ++r) {
    const int nB = q0B + grp * 4 + r;
    const int nA = q0A + grp * 4 + r;
#pragma unroll
    for (int c = 0; c < 4; ++c) {
      parO[(pbase + nB) * HD + c * 16 + lr] = f2bf(oB[c][r]);
      parO[(pbase + nA) * HD + c * 16 + lr] = f2bf(oA[c][r]);
    }
  }
}

// combine: AO[b][n][h*64+d] = (parO0+parO1+parO2) / (parL0+parL1+parL2)
__global__ __launch_bounds__(256)
void combine(const u16* __restrict__ parO, const float* __restrict__ parL,
             u16* __restrict__ AO)
{
  const int i = blockIdx.x * 256 + threadIdx.x;   // < 524288 (32*2048*8)
  const int bh = i >> 14;
  const int rem = i & 16383;
  const int n = rem >> 3;
  const int d0 = (rem & 7) * 8;
  const size_t q0 = (size_t)bh * SEQ + n;
  const float inv = 1.f / (parL[q0] + parL[q0 + 65536] + parL[q0 + 131072]);
  const u16* p0 = parO + q0 * HD + d0;
  const u16* p1 = p0 + (size_t)4194304;           // part-1 plane
  const u16* p2 = p0 + (size_t)8388608;           // part-2 plane
  bf16x8 a = *(const bf16x8*)p0;
  bf16x8 b = *(const bf16x8*)p1;
  bf16x8 cc = *(const bf16x8*)p2;
  bf16x8 o;
#pragma unroll
  for (int j = 0; j < 8; ++j)
    o[j] = (short)f2bf((bf2f((u16)a[j]) + bf2f((u16)b[j]) + bf2f((u16)cc[j])) * inv);
  const int bb = bh >> 4, h = bh & 15;
  *(bf16x8*)&AO[((size_t)(bb * SEQ + n)) * HID + h * HD + d0] = o;
}

extern "C" void kernel_launch(void* const* d_in, const int* in_sizes, int n_in,
                              void* d_out, int out_size, void* d_ws, size_t ws_size,
                              hipStream_t stream) {
  const float* q  = (const float*)d_in[0];
  const float* k  = (const float*)d_in[1];
  const float* v  = (const float*)d_in[2];
  /* d_in[3] = mask: tril by construction -> causal handled structurally */
  const float* Wq = (const float*)d_in[4];
  const float* bq = (const float*)d_in[5];
  const float* Wk = (const float*)d_in[6];
  const float* bk = (const float*)d_in[7];
  const float* Wv = (const float*)d_in[8];
  const float* bv = (const float*)d_in[9];
  const float* Wp = (const float*)d_in[10];
  const float* bp = (const float*)d_in[11];
  float* out = (float*)d_out;

  // ws (56 MiB), temporally aliased:
  //  phase 1 (conv+qkv): qb@0(8) kb@8(8) vb@16(8) Wcat@24(6) Wpb@30(2)
  //  phase 2 (attn):     parO@0(24, 3 planes) parL@24(0.79)  [qb..vb,Wcat dead]
  //  phase 3 (combine):  AO@32(8, aliases Qh — dead after attn)
  //  persistent:         Wpb@30(2) Kh@40(8) Vt@48(8)
  char* ws = (char*)d_ws;
  u16*   qb   = (u16*)(ws);
  u16*   kb   = (u16*)(ws + ( 8u << 20));
  u16*   vb   = (u16*)(ws + (16u << 20));
  u16*   Wcat = (u16*)(ws + (24u << 20));
  u16*   Wpb  = (u16*)(ws + (30u << 20));
  u16*   Qh   = (u16*)(ws + (32u << 20));
  u16*   Kh   = (u16*)(ws + (40u << 20));
  u16*   Vt   = (u16*)(ws + (48u << 20));
  u16*   parO = (u16*)(ws);                 // 24 MiB (3 planes of 8 MiB)
  float* parL = (float*)(ws + (24u << 20)); // 768 KiB (3 x 256 KiB)
  u16*   AO   = (u16*)(ws + (32u << 20));   // 8 MiB (aliases Qh)

  const float qscale = 0.125f * 1.4426950408889634f;  // 1/sqrt(64) * log2(e)

  conv_all<<<8192, 256, 0, stream>>>(q, k, v, Wq, Wk, Wv, Wp,
                                     qb, kb, vb, Wcat, Wpb);
  gemm_qkv<<<768, 256, 0, stream>>>(
      qb, kb, vb, Wcat, bq, bk, bv, Qh, Kh, Vt, qscale);
  attn_fwd<<<dim3(24, NB * NHEAD), 512, 0, stream>>>(Qh, Kh, Vt, parO, parL);
  combine<<<2048, 256, 0, stream>>>(parO, parL, AO);
  gemm_proj<<<512, 256, 0, stream>>>(AO, Wpb, bp, out);
}

// Round 21
// 116.350 us; speedup vs baseline: 1.0487x; 1.0487x over previous
//
#include <hip/hip_runtime.h>

typedef unsigned short u16;
typedef __attribute__((ext_vector_type(8))) short bf16x8;
typedef __attribute__((ext_vector_type(4))) short bf16x4;
typedef __attribute__((ext_vector_type(4))) float f32x4;

#define NB 2
#define SEQ 2048
#define HID 1024
#define NHEAD 16
#define HD 64
#define MROWS (NB * SEQ) /* 4096 */

__device__ __forceinline__ float bf2f(u16 u) {
  union { unsigned u; float f; } x; x.u = ((unsigned)u) << 16; return x.f;
}
__device__ __forceinline__ u16 f2bf(float f) {
  union { float f; unsigned u; } x; x.f = f;
  unsigned r = x.u + 0x7fffu + ((x.u >> 16) & 1u);
  return (u16)(r >> 16);
}
__device__ __forceinline__ u16 f2bf_trunc(float f) {
  union { float f; unsigned u; } x; x.f = f;
  return (u16)(x.u >> 16);
}

#define GLOAD_LDS16(g, l)                                                   \
  __builtin_amdgcn_global_load_lds(                                         \
      (const __attribute__((address_space(1))) void*)(g),                   \
      (__attribute__((address_space(3))) void*)(l), 16, 0, 0)

// all-tensor f32 -> bf16: q,k,v (4M elems each) + Wq,Wk,Wv -> Wcat + Wp -> Wpb
__global__ __launch_bounds__(256)
void conv_all(const float* __restrict__ q, const float* __restrict__ k,
              const float* __restrict__ v, const float* __restrict__ wq,
              const float* __restrict__ wk, const float* __restrict__ wv,
              const float* __restrict__ wp, u16* __restrict__ qb,
              u16* __restrict__ kb, u16* __restrict__ vb,
              u16* __restrict__ wcat, u16* __restrict__ wpb)
{
  const int i = blockIdx.x * 256 + threadIdx.x;  // vec8 index, < 2097152
  const float* s; u16* d;
  if (i < 1572864) {
    const int seg = i / 524288;          // 0=q 1=k 2=v
    const int off = i - seg * 524288;
    s = (seg == 0 ? q : seg == 1 ? k : v) + (size_t)off * 8;
    d = (seg == 0 ? qb : seg == 1 ? kb : vb) + (size_t)off * 8;
  } else {
    const int j = i - 1572864;
    const int seg = j / 131072;          // 0=Wq 1=Wk 2=Wv 3=Wp
    const int off = j - seg * 131072;
    s = (seg == 0 ? wq : seg == 1 ? wk : seg == 2 ? wv : wp) + (size_t)off * 8;
    d = (seg < 3 ? wcat + (size_t)seg * 1048576 : wpb) + (size_t)off * 8;
  }
  f32x4 a = *(const f32x4*)s;
  f32x4 b = *(const f32x4*)(s + 4);
  bf16x8 o;
#pragma unroll
  for (int j = 0; j < 4; ++j) { o[j] = (short)f2bf(a[j]); o[4 + j] = (short)f2bf(b[j]); }
  *(bf16x8*)d = o;
}

// Fused QKV projection GEMM, 128x128x32. 3-buffer, 2-ahead prefetch,
// counted vmcnt(4). LDS 48 KB, 3 blocks/CU uniform (grid 768). XOR chunk
// swizzle (chunk ^= (row>>1)&3, pre-swizzled source). XCD-pinned groups.
__global__ __launch_bounds__(256)
void gemm_qkv(const u16* __restrict__ A0, const u16* __restrict__ A1,
              const u16* __restrict__ A2, const u16* __restrict__ Wcat,
              const float* __restrict__ b0, const float* __restrict__ b1,
              const float* __restrict__ b2,
              u16* __restrict__ Qh, u16* __restrict__ Kh, u16* __restrict__ Vt,
              float qscale)
{
  __shared__ u16 As[3 * 128 * 32];   // 24 KB (3 bufs x 8 KB)
  __shared__ u16 Bs[3 * 128 * 32];   // 24 KB
  const int p = blockIdx.x;
  const int c = p & 7;                 // presumed XCD (round-robin dispatch)
  const int i_ = p >> 3;               // [0,96)
  const int G = c * 12 + (i_ % 12);    // group: 8 members share A rows + XCD
  const int j = i_ / 12;               // member = n-subtile [0,8)
  const int g = G >> 5;                // tensor select 0..2 (q/k/v)
  const int m0 = (G & 31) * 128;       // m-tile
  const int n0 = (g * 8 + j) * 128;    // Wcat row base
  const u16* A = (g == 0) ? A0 : (g == 1) ? A1 : A2;
  const float* bias = (g == 0) ? b0 : (g == 1) ? b1 : b2;
  const int t = threadIdx.x, lane = t & 63, w = t >> 6;
  const int grp = lane >> 4, lr = lane & 15;
  const int wr = (w >> 1) * 64, wc = (w & 1) * 64;
  const int sw2 = (lr >> 1) & 3;       // read-side XOR

  f32x4 acc[4][4];
#pragma unroll
  for (int i = 0; i < 4; ++i)
#pragma unroll
    for (int j2 = 0; j2 < 4; ++j2) acc[i][j2] = (f32x4){0.f, 0.f, 0.f, 0.f};

  const int srow4 = lane >> 2;
  const int csrc = ((lane & 3) ^ ((lane >> 3) & 3)) * 8;
  const u16* ag = A + (size_t)(m0 + w * 32 + srow4) * HID + csrc;
  const u16* wg = Wcat + (size_t)(n0 + w * 32 + srow4) * HID + csrc;

#define STAGE(BI, K0)                                                \
  {                                                                  \
    const u16* ab = ag + (K0);                                       \
    const u16* wb = wg + (K0);                                       \
    u16* al = As + (BI) * 4096 + (w * 32) * 32;                      \
    u16* bl = Bs + (BI) * 4096 + (w * 32) * 32;                      \
    GLOAD_LDS16(ab, al);                                             \
    GLOAD_LDS16(ab + (size_t)16 * HID, al + 16 * 32);                \
    GLOAD_LDS16(wb, bl);                                             \
    GLOAD_LDS16(wb + (size_t)16 * HID, bl + 16 * 32);                \
  }

  STAGE(0, 0);
  STAGE(1, 32);

  for (int it = 0; it < 32; ++it) {
    const int cur = it % 3;
    if (it < 31) asm volatile("s_waitcnt vmcnt(4)" ::: "memory");
    else         asm volatile("s_waitcnt vmcnt(0)" ::: "memory");
    __builtin_amdgcn_s_barrier();
    __builtin_amdgcn_sched_barrier(0);
    asm volatile("" ::: "memory");
    if (it < 30) STAGE((it + 2) % 3, (it + 2) * 32);
    const u16* Ab = As + cur * 4096;
    const u16* Bb = Bs + cur * 4096;
    bf16x8 af[4], bf[4];
#pragma unroll
    for (int mi = 0; mi < 4; ++mi)
      af[mi] = *(const bf16x8*)&Ab[(wr + mi * 16 + lr) * 32 +
                                   (((grp ^ sw2)) * 8)];
#pragma unroll
    for (int ni = 0; ni < 4; ++ni)
      bf[ni] = *(const bf16x8*)&Bb[(wc + ni * 16 + lr) * 32 +
                                   (((grp ^ sw2)) * 8)];
    __builtin_amdgcn_s_setprio(1);
#pragma unroll
    for (int mi = 0; mi < 4; ++mi)
#pragma unroll
      for (int ni = 0; ni < 4; ++ni)
        acc[mi][ni] = __builtin_amdgcn_mfma_f32_16x16x32_bf16(
            af[mi], bf[ni], acc[mi][ni], 0, 0, 0);
    __builtin_amdgcn_s_setprio(0);
  }
#undef STAGE

  const float scale = (g == 0) ? qscale : 1.f;
#pragma unroll
  for (int mi = 0; mi < 4; ++mi) {
#pragma unroll
    for (int ni = 0; ni < 4; ++ni) {
      const int nl = (n0 & (HID - 1)) + wc + ni * 16 + lr;  // within-tensor col
      const float bval = bias[nl];
      const int mb = m0 + wr + mi * 16 + grp * 4;
      const int h = nl >> 6, d = nl & (HD - 1);
      if (g == 2) {  // V transposed: vector over r (m-contiguous)
        const int b = mb >> 11, nn = mb & (SEQ - 1);
        bf16x4 pk;
#pragma unroll
        for (int r = 0; r < 4; ++r)
          pk[r] = (short)f2bf(acc[mi][ni][r] + bval);
        *(bf16x4*)&Vt[((size_t)(b * NHEAD + h) * HD + d) * SEQ + nn] = pk;
      } else {
        u16* O = (g == 0) ? Qh : Kh;
#pragma unroll
        for (int r = 0; r < 4; ++r) {
          const int m = mb + r;
          const int b = m >> 11, nn = m & (SEQ - 1);
          O[((size_t)(b * NHEAD + h) * SEQ + nn) * HD + d] =
              f2bf((acc[mi][ni][r] + bval) * scale);
        }
      }
    }
  }
}

// Output projection GEMM, 128x64x64 (proven config — unchanged).
__global__ __launch_bounds__(256)
void gemm_proj(const u16* __restrict__ A, const u16* __restrict__ W,
               const float* __restrict__ bias, float* __restrict__ Op)
{
  __shared__ u16 As[2 * 128 * 64];   // 32 KB
  __shared__ u16 Bs[2 * 64 * 64];    // 16 KB
  const int p = blockIdx.x;
  const int cx = p & 7;
  const int i_ = p >> 3;               // [0,64)
  const int G = cx * 4 + (i_ & 3);     // m-tile [0,32), pinned to XCD cx
  const int j = i_ >> 2;               // n-member [0,16)
  const int m0 = G * 128, n0 = j * 64;
  const int t = threadIdx.x, lane = t & 63, w = t >> 6;
  const int grp = lane >> 4, lr = lane & 15;
  const int wr = (w >> 1) * 64, wc = (w & 1) * 32;
  const int sw8 = lr & 7;

  f32x4 acc[4][2];
#pragma unroll
  for (int i = 0; i < 4; ++i)
#pragma unroll
    for (int j2 = 0; j2 < 2; ++j2) acc[i][j2] = (f32x4){0.f, 0.f, 0.f, 0.f};

  const int srow8 = lane >> 3;
  const int achunk = ((lane & 7) ^ srow8) * 8;
  const u16* ag = A + (size_t)(m0 + w * 32 + srow8) * HID + achunk;
  const u16* wg = W + (size_t)(n0 + w * 16 + srow8) * HID + achunk;

#define STAGE(BI, K0)                                                \
  {                                                                  \
    const u16* ab = ag + (K0);                                       \
    const u16* wb = wg + (K0);                                       \
    u16* al = As + (BI) * 8192 + (w * 32) * 64;                      \
    u16* bl = Bs + (BI) * 4096 + (w * 16) * 64;                      \
    GLOAD_LDS16(ab, al);                                             \
    GLOAD_LDS16(ab + (size_t)8 * HID, al + 8 * 64);                  \
    GLOAD_LDS16(ab + (size_t)16 * HID, al + 16 * 64);                \
    GLOAD_LDS16(ab + (size_t)24 * HID, al + 24 * 64);                \
    GLOAD_LDS16(wb, bl);                                             \
    GLOAD_LDS16(wb + (size_t)8 * HID, bl + 8 * 64);                  \
  }

  STAGE(0, 0);

  for (int it = 0; it < 16; ++it) {
    const int cur = it & 1;
    asm volatile("s_waitcnt vmcnt(0)" ::: "memory");
    __builtin_amdgcn_s_barrier();
    __builtin_amdgcn_sched_barrier(0);
    asm volatile("" ::: "memory");
    if (it < 15) STAGE(cur ^ 1, (it + 1) * 64);
    const u16* Ab = As + cur * 8192;
    const u16* Bb = Bs + cur * 4096;
#pragma unroll
    for (int kh = 0; kh < 2; ++kh) {
      bf16x8 af[4], bf[2];
#pragma unroll
      for (int mi = 0; mi < 4; ++mi)
        af[mi] = *(const bf16x8*)&Ab[(wr + mi * 16 + lr) * 64 +
                                     (((kh * 4 + grp) ^ sw8) * 8)];
#pragma unroll
      for (int ni = 0; ni < 2; ++ni)
        bf[ni] = *(const bf16x8*)&Bb[(wc + ni * 16 + lr) * 64 +
                                     (((kh * 4 + grp) ^ sw8) * 8)];
      __builtin_amdgcn_s_setprio(1);
#pragma unroll
      for (int mi = 0; mi < 4; ++mi)
#pragma unroll
        for (int ni = 0; ni < 2; ++ni)
          acc[mi][ni] = __builtin_amdgcn_mfma_f32_16x16x32_bf16(
              af[mi], bf[ni], acc[mi][ni], 0, 0, 0);
      __builtin_amdgcn_s_setprio(0);
    }
  }
#undef STAGE

#pragma unroll
  for (int mi = 0; mi < 4; ++mi) {
#pragma unroll
    for (int ni = 0; ni < 2; ++ni) {
      const int n = n0 + wc + ni * 16 + lr;
      const float bval = bias[n];
      const int mb = m0 + wr + mi * 16 + grp * 4;
#pragma unroll
      for (int rr = 0; rr < 4; ++rr)
        Op[(size_t)(mb + rr) * HID + n] = acc[mi][ni][rr] + bval;
    }
  }
}

// Causal flash attention, PAIRED q-tiles + PARITY-INTERLEAVED KV SPLIT
// (measured-best config: 2-buffer, vmcnt(0), 2-way parity; 3-way split
// and 2-ahead prefetch both regressed). No-max softmax -> additive
// partials parO/parL. QBLK=128, KVBLK=64, grid 512 = 2 blocks/CU.
__global__ __launch_bounds__(512)
void attn_fwd(const u16* __restrict__ Q, const u16* __restrict__ K,
              const u16* __restrict__ Vt, u16* __restrict__ parO,
              float* __restrict__ parL)
{
  __shared__ u16 KB[2][4096];
  __shared__ u16 VB[2][4096];
  const int bh = blockIdx.y;
  const int t = threadIdx.x;
  const int w = t >> 6, lane = t & 63;
  const int grp = lane >> 4, lr = lane & 15;
  const int px = blockIdx.x;           // [0,16)
  const int parity = px & 1;
  const int qtA = px >> 1;             // 0..7
  const int qtB = 15 - qtA;            // 8..15
  const int q0A = qtA * 128 + w * 16;
  const int q0B = qtB * 128 + w * 16;
  const int ntB = 2 * qtB + 2;
  const size_t base = (size_t)bh * SEQ * HD;
  const float NEGINF = -__builtin_inff();

  const int srow = lane >> 3;
  const int scol = (lane & 7) ^ srow;
  const u16* kg = K + base + (size_t)(w * 8 + srow) * HD + scol * 8;
  const u16* vg = Vt + base + (size_t)(w * 8 + srow) * SEQ + scol * 8;

  const bf16x8 aqA0 = *(const bf16x8*)&Q[base + (size_t)(q0A + lr) * HD + grp * 8];
  const bf16x8 aqA1 = *(const bf16x8*)&Q[base + (size_t)(q0A + lr) * HD + grp * 8 + 32];
  const bf16x8 aqB0 = *(const bf16x8*)&Q[base + (size_t)(q0B + lr) * HD + grp * 8];
  const bf16x8 aqB1 = *(const bf16x8*)&Q[base + (size_t)(q0B + lr) * HD + grp * 8 + 32];

  float lA = 0.f, lB = 0.f;
  f32x4 oA[4], oB[4];
#pragma unroll
  for (int c = 0; c < 4; ++c) {
    oA[c] = (f32x4){0.f, 0.f, 0.f, 0.f};
    oB[c] = (f32x4){0.f, 0.f, 0.f, 0.f};
  }

  const int idqA = q0A >> 6;
  const int idqB = q0B >> 6;
  const int sw = lr & 7;

#define STAGE(bi, j0)                                              \
  {                                                                \
    GLOAD_LDS16(kg + (size_t)(j0) * HD, &KB[bi][w * 512]);         \
    GLOAD_LDS16(vg + (j0), &VB[bi][w * 512]);                      \
  }

#define COMPUTE(Q0, AQ0, AQ1, OACC, LI, IDQ)                                  \
  do {                                                                        \
    f32x4 sv[4];                                                              \
    __builtin_amdgcn_s_setprio(1);                                            \
    _Pragma("unroll")                                                         \
    for (int st = 0; st < 4; ++st) {                                          \
      const int ro = (st * 16 + lr) * 64;                                     \
      bf16x8 k0 = *(const bf16x8*)&KB[bi][ro + ((grp ^ sw) * 8)];             \
      bf16x8 k1 = *(const bf16x8*)&KB[bi][ro + (((grp + 4) ^ sw) * 8)];       \
      f32x4 s = (f32x4){0.f, 0.f, 0.f, 0.f};                                  \
      s = __builtin_amdgcn_mfma_f32_16x16x32_bf16(k0, (AQ0), s, 0, 0, 0);     \
      s = __builtin_amdgcn_mfma_f32_16x16x32_bf16(k1, (AQ1), s, 0, 0, 0);     \
      sv[st] = s;                                                             \
    }                                                                         \
    __builtin_amdgcn_s_setprio(0);                                            \
    bf16x4 bv[4][4];                                                          \
    _Pragma("unroll")                                                         \
    for (int st = 0; st < 4; ++st)                                            \
      _Pragma("unroll")                                                       \
      for (int c = 0; c < 4; ++c)                                             \
        bv[st][c] = *(const bf16x4*)&VB[bi][(c * 16 + lr) * 64 +              \
                        (((st * 2 + (grp >> 1)) ^ sw) * 8) + (grp & 1) * 4];  \
    if (it == (IDQ)) {                                                        \
      const int j0 = it << 6, qg = (Q0) + lr;                                 \
      _Pragma("unroll")                                                       \
      for (int st = 0; st < 4; ++st)                                          \
        _Pragma("unroll")                                                     \
        for (int r = 0; r < 4; ++r)                                           \
          if (j0 + st * 16 + grp * 4 + r > qg) sv[st][r] = NEGINF;            \
    }                                                                         \
    float rs = 0.f;                                                           \
    _Pragma("unroll")                                                         \
    for (int st = 0; st < 4; ++st)                                            \
      _Pragma("unroll")                                                       \
      for (int r = 0; r < 4; ++r) {                                           \
        sv[st][r] = exp2f(sv[st][r]);                                         \
        rs += sv[st][r];                                                      \
      }                                                                       \
    (LI) += rs;                                                               \
    bf16x4 pa[4];                                                             \
    _Pragma("unroll")                                                         \
    for (int st = 0; st < 4; ++st)                                            \
      _Pragma("unroll")                                                       \
      for (int r = 0; r < 4; ++r) pa[st][r] = (short)f2bf_trunc(sv[st][r]);   \
    __builtin_amdgcn_s_setprio(1);                                            \
    _Pragma("unroll")                                                         \
    for (int st = 0; st < 4; ++st)                                            \
      _Pragma("unroll")                                                       \
      for (int c = 0; c < 4; ++c)                                             \
        (OACC)[c] = __builtin_amdgcn_mfma_f32_16x16x16bf16_1k(                \
            pa[st], bv[st][c], (OACC)[c], 0, 0, 0);                           \
    __builtin_amdgcn_s_setprio(0);                                            \
  } while (0)

  STAGE(0, parity << 6);

  for (int it = parity; it < ntB; it += 2) {
    const int bi = ((it - parity) >> 1) & 1;
    asm volatile("s_waitcnt vmcnt(0)" ::: "memory");
    __builtin_amdgcn_s_barrier();
    __builtin_amdgcn_sched_barrier(0);
    asm volatile("" ::: "memory");
    if (it + 2 < ntB) STAGE(bi ^ 1, (it + 2) << 6);

    if (it <= idqB) COMPUTE(q0B, aqB0, aqB1, oB, lB, idqB);
    if (it <= idqA) COMPUTE(q0A, aqA0, aqA1, oA, lA, idqA);
  }
#undef STAGE
#undef COMPUTE

  lB += __shfl_xor(lB, 16);  lB += __shfl_xor(lB, 32);
  lA += __shfl_xor(lA, 16);  lA += __shfl_xor(lA, 32);

  const size_t pbase = (size_t)(parity * 32 + bh) * SEQ;
  if (grp == 0) {
    parL[pbase + q0B + lr] = lB;
    parL[pbase + q0A + lr] = lA;
  }
#pragma unroll
  for (int r = 0; r < 4; ++r) {
    const int nB = q0B + grp * 4 + r;
    const int nA = q0A + grp * 4 + r;
#pragma unroll
    for (int c = 0; c < 4; ++c) {
      parO[(pbase + nB) * HD + c * 16 + lr] = f2bf(oB[c][r]);
      parO[(pbase + nA) * HD + c * 16 + lr] = f2bf(oA[c][r]);
    }
  }
}

// combine: AO[b][n][h*64+d] = (parO0 + parO1) / (parL0 + parL1)
__global__ __launch_bounds__(256)
void combine(const u16* __restrict__ parO, const float* __restrict__ parL,
             u16* __restrict__ AO)
{
  const int i = blockIdx.x * 256 + threadIdx.x;   // < 524288 (32*2048*8)
  const int bh = i >> 14;
  const int rem = i & 16383;
  const int n = rem >> 3;
  const int d0 = (rem & 7) * 8;
  const size_t q0 = (size_t)bh * SEQ + n;
  const float inv = 1.f / (parL[q0] + parL[q0 + 65536]);
  const u16* p0 = parO + q0 * HD + d0;
  const u16* p1 = p0 + (size_t)4194304;           // parity-1 plane
  bf16x8 a = *(const bf16x8*)p0;
  bf16x8 b = *(const bf16x8*)p1;
  bf16x8 o;
#pragma unroll
  for (int j = 0; j < 8; ++j)
    o[j] = (short)f2bf((bf2f((u16)a[j]) + bf2f((u16)b[j])) * inv);
  const int bb = bh >> 4, h = bh & 15;
  *(bf16x8*)&AO[((size_t)(bb * SEQ + n)) * HID + h * HD + d0] = o;
}

extern "C" void kernel_launch(void* const* d_in, const int* in_sizes, int n_in,
                              void* d_out, int out_size, void* d_ws, size_t ws_size,
                              hipStream_t stream) {
  const float* q  = (const float*)d_in[0];
  const float* k  = (const float*)d_in[1];
  const float* v  = (const float*)d_in[2];
  /* d_in[3] = mask: tril by construction -> causal handled structurally */
  const float* Wq = (const float*)d_in[4];
  const float* bq = (const float*)d_in[5];
  const float* Wk = (const float*)d_in[6];
  const float* bk = (const float*)d_in[7];
  const float* Wv = (const float*)d_in[8];
  const float* bv = (const float*)d_in[9];
  const float* Wp = (const float*)d_in[10];
  const float* bp = (const float*)d_in[11];
  float* out = (float*)d_out;

  // ws (56 MiB), temporally aliased:
  //  phase 1 (conv+qkv): qb@0(8) kb@8(8) vb@16(8) Wcat@24(6) Wpb@30(2)
  //  phase 2 (attn):     parO@0(17) parL@17(0.5)   [qb..vb dead after qkv]
  //  phase 3 (combine):  AO@18(8)                   [Wcat dead after qkv]
  //  persistent:         Wpb@30(2) Qh@32(8) Kh@40(8) Vt@48(8)
  char* ws = (char*)d_ws;
  u16*   qb   = (u16*)(ws);
  u16*   kb   = (u16*)(ws + ( 8u << 20));
  u16*   vb   = (u16*)(ws + (16u << 20));
  u16*   Wcat = (u16*)(ws + (24u << 20));
  u16*   Wpb  = (u16*)(ws + (30u << 20));
  u16*   Qh   = (u16*)(ws + (32u << 20));
  u16*   Kh   = (u16*)(ws + (40u << 20));
  u16*   Vt   = (u16*)(ws + (48u << 20));
  u16*   parO = (u16*)(ws);                 // 16.78 MiB (aliases qb/kb/vb)
  float* parL = (float*)(ws + (17u << 20)); // 512 KiB
  u16*   AO   = (u16*)(ws + (18u << 20));   // 8 MiB (Wcat dead by then)

  const float qscale = 0.125f * 1.4426950408889634f;  // 1/sqrt(64) * log2(e)

  conv_all<<<8192, 256, 0, stream>>>(q, k, v, Wq, Wk, Wv, Wp,
                                     qb, kb, vb, Wcat, Wpb);
  gemm_qkv<<<768, 256, 0, stream>>>(
      qb, kb, vb, Wcat, bq, bk, bv, Qh, Kh, Vt, qscale);
  attn_fwd<<<dim3(16, NB * NHEAD), 512, 0, stream>>>(Qh, Kh, Vt, parO, parL);
  combine<<<2048, 256, 0, stream>>>(parO, parL, AO);
  gemm_proj<<<512, 256, 0, stream>>>(AO, Wpb, bp, out);
}